// Round 1
// 103.172 us; speedup vs baseline: 1.0139x; 1.0139x over previous
//
#include <hip/hip_runtime.h>
#include <math.h>

// Problem constants
constexpr int L   = 4096;   // seq len
constexpr int D   = 1024;   // d_model
constexpr int N   = 16;     // hiddens per channel
constexpr int CPB = 4;      // channels per block
constexpr int NB  = D / CPB;   // 256 blocks (1 per CU)
constexpr int NCB = 128;    // chunks per block
constexpr int T   = L / NCB;   // 32 steps per chunk
constexpr int NT  = 1024;   // threads per block (16 waves, 4/SIMD)
constexpr int PAD = 65;     // sums chunk stride in float2 (64 -> 65 kills the
                            // 32-way bank conflict: bank = 2*ct+16*h+4p, only
                            // the 4 dd lanes alias -> 4-way, ~free per m136)

typedef float v2 __attribute__((ext_vector_type(2)));

__device__ __forceinline__ float softplus_f(float v) {
    return fmaxf(v, 0.0f) + log1pf(expf(-fabsf(v)));
}

// Fast Lambda = exp(dt*(ar + i*ai)) via HW transcendentals.
__device__ __forceinline__ void lam_fast(float ar, float ai, float dt,
                                         float& lr, float& li) {
    float e = __expf(ar * dt);
    float s, c;
    __sincosf(ai * dt, &s, &c);
    lr = e * c;
    li = e * s;
}

__device__ __forceinline__ v2 vfma(v2 a, v2 b, v2 c) {
    return __builtin_elementwise_fma(a, b, c);
}

// One dispatch, 256 blocks (1/CU). Block owns channels [d0, d0+4) x full L.
// Thread t: h = t&1 (n-half, 8 states), dd = (t>>1)&3 (channel), ct = t>>3
// (chunk of T=32). All cross-thread dataflow is intra-block (LDS + shfl).
//   0) stage x slice via float4 loads (16 B/lane)   -> xs[i][ct][dd], 64 KB
//   1) local scan of chunk ct (packed fp32)         -> sums[ct][dd*16+n]
//   2) 3-pass parallel chunk scan (was: 128-step serial scan on wave 0):
//      p1: each wave w scans its 8 chunks (exclusive), totals -> tot[w]
//      p2: wave 0 scans the 16 wave-totals with ratio Lam^256
//      p3: each wave adds Lam^(32k)*G_w to its local prefixes
//   3) rescan from carry, contract C'=dt*C*B, h-shfl reduce, then 4-lane
//      in-register transpose (3 shfl_xor) -> one float4 row-segment store
//      per lane (16 B/lane, fully-packed store granularity)
// d0 swizzle: blocks b, b+8, b+16, b+24 (same XCD under round-robin) share
// each 64 B x-line -> HBM fetch stays ~16 MB, reuse served by that XCD's L2.
__global__ __launch_bounds__(NT, 4) void k_fused(
    const float* __restrict__ x,
    const float* __restrict__ Delta,
    const float* __restrict__ A_re, const float* __restrict__ A_im,
    const float* __restrict__ B_re, const float* __restrict__ B_im,
    const float* __restrict__ C_re, const float* __restrict__ C_im,
    const float* __restrict__ Dp,
    float* __restrict__ out)
{
    __shared__ float  xs[T * 512];        // [i][ct][dd]: word i*512+ct*4+dd
    __shared__ float2 sums[NCB * PAD];    // [ct][dd*16+n], padded, 66.5 KB
    __shared__ float2 tot[16 * 64];       // per-wave totals/carries, 8 KB

    const int b  = blockIdx.x;
    const int d0 = (b & 7) * 128 + (b >> 3) * 4;   // XCD-contiguous channels
    const int t  = threadIdx.x;

    // ---- phase 0: stage x[0..L) x [d0, d0+4) into LDS, float4 loads ----
    {
        const int sct = t & 127;          // chunk
        const int si  = t >> 7;           // 0..7: which 4-row group
        float4 v[4];
        #pragma unroll
        for (int k = 0; k < 4; ++k) {
            int l = sct * T + si * 4 + k;
            v[k] = *(const float4*)(x + (size_t)l * D + d0);
        }
        #pragma unroll
        for (int k = 0; k < 4; ++k)
            *(float4*)&xs[(si * 4 + k) * 512 + sct * 4] = v[k];
    }

    const int h  = t & 1;
    const int dd = (t >> 1) & 3;
    const int ct = t >> 3;
    const int d  = d0 + dd;
    const float dt = softplus_f(Delta[d]);

    // ---- per-thread Lambda for its 8 states (n = h*8..h*8+7), packed ----
    v2 LR[4], LI[4];
    {
        const int base = d * N + h * 8;
        float4 a0 = *(const float4*)(A_re + base);
        float4 a1 = *(const float4*)(A_re + base + 4);
        float4 m0 = *(const float4*)(A_im + base);
        float4 m1 = *(const float4*)(A_im + base + 4);
        const float ar[8] = {a0.x, a0.y, a0.z, a0.w, a1.x, a1.y, a1.z, a1.w};
        const float ai[8] = {m0.x, m0.y, m0.z, m0.w, m1.x, m1.y, m1.z, m1.w};
        #pragma unroll
        for (int p = 0; p < 4; ++p) {
            float lr0, li0, lr1, li1;
            lam_fast(ar[2 * p], ai[2 * p], dt, lr0, li0);
            lam_fast(ar[2 * p + 1], ai[2 * p + 1], dt, lr1, li1);
            LR[p] = (v2){lr0, lr1};
            LI[p] = (v2){li0, li1};
        }
    }
    __syncthreads();   // xs ready

    // ---- phase 1: local scan of chunk ct, zero init ----
    v2 GR[4] = {(v2)0, (v2)0, (v2)0, (v2)0};
    v2 GI[4] = {(v2)0, (v2)0, (v2)0, (v2)0};
    #pragma unroll 4
    for (int i = 0; i < T; ++i) {
        float xv = xs[i * 512 + ct * 4 + dd];
        v2 XV = (v2){xv, xv};
        #pragma unroll
        for (int p = 0; p < 4; ++p) {
            v2 t2 = vfma(-LI[p], GI[p], XV);
            v2 nr = vfma(LR[p], GR[p], t2);
            GI[p] = vfma(LR[p], GI[p], LI[p] * GR[p]);
            GR[p] = nr;
        }
    }
    {
        float2* sp = &sums[ct * PAD + dd * 16 + h * 8];
        #pragma unroll
        for (int p = 0; p < 4; ++p) {
            sp[2 * p]     = make_float2(GR[p].x, GI[p].x);
            sp[2 * p + 1] = make_float2(GR[p].y, GI[p].y);
        }
    }
    __syncthreads();   // summaries ready

    // ---- phase 2: parallel scan over the 128 chunk summaries ----
    // Lane roles: lane = (dd2, n2) pair (64 lanes = all pairs), wave w owns
    // chunks [8w, 8w+8).
    const int lane = t & 63;
    const int w    = t >> 6;
    float l32r, l32i;           // Lambda^32 for this lane's (dd2, n2)
    {
        const int dd2 = lane >> 4, n2 = lane & 15;
        const int d2  = d0 + dd2;
        const float dt2 = softplus_f(Delta[d2]);
        lam_fast(A_re[d2 * N + n2], A_im[d2 * N + n2], dt2, l32r, l32i);
        #pragma unroll
        for (int k = 0; k < 5; ++k) {     // Lam^32 (T = 32)
            float nr = l32r * l32r - l32i * l32i;
            l32i = 2.0f * l32r * l32i;
            l32r = nr;
        }
    }
    // pass 1: per-wave exclusive scan of its 8 chunks; total -> tot[w]
    {
        float cr = 0.0f, ci = 0.0f;
        #pragma unroll
        for (int k = 0; k < 8; ++k) {
            const int idx = (w * 8 + k) * PAD + lane;
            float2 sv = sums[idx];
            sums[idx] = make_float2(cr, ci);     // local exclusive prefix P
            float nr = fmaf(l32r, cr, fmaf(-l32i, ci, sv.x));
            ci = fmaf(l32r, ci, fmaf(l32i, cr, sv.y));
            cr = nr;
        }
        tot[w * 64 + lane] = make_float2(cr, ci);   // S_w
    }
    __syncthreads();   // all wave totals ready

    // ---- phase 3 params: issue global loads now so they fly during pass 2 ----
    float4 b0, b1, e0, e1, f0, f1, g0, g1;
    {
        const int base = d * N + h * 8;
        b0 = *(const float4*)(B_re + base);
        b1 = *(const float4*)(B_re + base + 4);
        e0 = *(const float4*)(B_im + base);
        e1 = *(const float4*)(B_im + base + 4);
        f0 = *(const float4*)(C_re + base);
        f1 = *(const float4*)(C_re + base + 4);
        g0 = *(const float4*)(C_im + base);
        g1 = *(const float4*)(C_im + base + 4);
    }
    const float dpv = Dp[d];

    // pass 2: wave 0 scans the 16 wave-totals with ratio Lam^256
    if (t < 64) {
        float rr = l32r, ri = l32i;
        #pragma unroll
        for (int k = 0; k < 3; ++k) {     // Lam^256 = (Lam^32)^8
            float nr = rr * rr - ri * ri;
            ri = 2.0f * rr * ri;
            rr = nr;
        }
        float cr = 0.0f, ci = 0.0f;
        #pragma unroll
        for (int u = 0; u < 16; ++u) {
            float2 sv = tot[u * 64 + t];
            tot[u * 64 + t] = make_float2(cr, ci);   // exclusive G_w
            float nr = fmaf(rr, cr, fmaf(-ri, ci, sv.x));
            ci = fmaf(rr, ci, fmaf(ri, cr, sv.y));
            cr = nr;
        }
    }
    __syncthreads();   // wave carries G_w ready

    // pass 3: C_{8w+k} = Lam^(32k) * G_w + P_{w,k}
    {
        float2 g = tot[w * 64 + lane];
        float gr = g.x, gi = g.y;
        #pragma unroll
        for (int k = 0; k < 8; ++k) {
            const int idx = (w * 8 + k) * PAD + lane;
            float2 p = sums[idx];
            sums[idx] = make_float2(gr + p.x, gi + p.y);
            float nr = l32r * gr - l32i * gi;
            gi = fmaf(l32r, gi, l32i * gr);
            gr = nr;
        }
    }

    // ---- phase 3 params: C' = dt*(C*B), D (packed) ----
    v2 CR[4], CI[4];
    {
        const float br[8] = {b0.x, b0.y, b0.z, b0.w, b1.x, b1.y, b1.z, b1.w};
        const float bi[8] = {e0.x, e0.y, e0.z, e0.w, e1.x, e1.y, e1.z, e1.w};
        const float cr[8] = {f0.x, f0.y, f0.z, f0.w, f1.x, f1.y, f1.z, f1.w};
        const float ci[8] = {g0.x, g0.y, g0.z, g0.w, g1.x, g1.y, g1.z, g1.w};
        #pragma unroll
        for (int p = 0; p < 4; ++p) {
            CR[p] = (v2){dt * (cr[2*p] * br[2*p] - ci[2*p] * bi[2*p]),
                         dt * (cr[2*p+1] * br[2*p+1] - ci[2*p+1] * bi[2*p+1])};
            CI[p] = (v2){dt * (cr[2*p] * bi[2*p] + ci[2*p] * br[2*p]),
                         dt * (cr[2*p+1] * bi[2*p+1] + ci[2*p+1] * br[2*p+1])};
        }
    }
    __syncthreads();   // carries ready (cross-lane within wave + cross-wave)

    // ---- phase 3: rescan from carry, contract, transpose-store ----
    {
        const float2* cp = &sums[ct * PAD + dd * 16 + h * 8];
        #pragma unroll
        for (int p = 0; p < 4; ++p) {
            float2 c0 = cp[2 * p], c1 = cp[2 * p + 1];
            GR[p] = (v2){c0.x, c1.x};
            GI[p] = (v2){c0.y, c1.y};
        }
    }
    #pragma unroll
    for (int ob = 0; ob < T / 8; ++ob) {
        float Vh[4];
        #pragma unroll
        for (int ib = 0; ib < 4; ++ib) {
            #pragma unroll
            for (int u = 0; u < 2; ++u) {
                int i = ob * 8 + ib * 2 + u;
                float xv = xs[i * 512 + ct * 4 + dd];
                v2 XV = (v2){xv, xv};
                v2 ACC = (v2)0;
                #pragma unroll
                for (int p = 0; p < 4; ++p) {
                    v2 t2 = vfma(-LI[p], GI[p], XV);
                    v2 nr = vfma(LR[p], GR[p], t2);
                    GI[p] = vfma(LR[p], GI[p], LI[p] * GR[p]);
                    GR[p] = nr;
                    ACC = vfma(CR[p], GR[p], ACC);
                    ACC = vfma(-CI[p], GI[p], ACC);
                }
                float acc = ACC.x + ACC.y;
                acc += __shfl_xor(acc, 1);       // combine the two n-halves
                acc = fmaf(dpv, xv, acc);        // finished value for (row,col d)
                if (u == h) Vh[ib] = acc;        // lane keeps its row parity
            }
        }
        // 4-lane transpose over dd (lane bits 1..2): lane (h,dd) assembles the
        // full 4-channel segment of row rr = ob*8 + dd*2 + h.
        // shfl_xor(Vh[dd^k], mask k<<1): partner dd^k sends Vh[(dd^k)^k == my dd].
        float f[4];
        f[dd]     = Vh[dd];
        f[dd ^ 1] = __shfl_xor(Vh[dd ^ 1], 2);
        f[dd ^ 2] = __shfl_xor(Vh[dd ^ 2], 4);
        f[dd ^ 3] = __shfl_xor(Vh[dd ^ 3], 6);
        int row = ct * T + ob * 8 + dd * 2 + h;
        *(float4*)(out + (size_t)row * D + d0) =
            make_float4(f[0], f[1], f[2], f[3]);   // 16 B/lane store
    }
}

extern "C" void kernel_launch(void* const* d_in, const int* in_sizes, int n_in,
                              void* d_out, int out_size, void* d_ws, size_t ws_size,
                              hipStream_t stream) {
    const float* x     = (const float*)d_in[0];
    const float* Delta = (const float*)d_in[1];
    const float* A_re  = (const float*)d_in[2];
    const float* A_im  = (const float*)d_in[3];
    const float* B_re  = (const float*)d_in[4];
    const float* B_im  = (const float*)d_in[5];
    const float* C_re  = (const float*)d_in[6];
    const float* C_im  = (const float*)d_in[7];
    const float* Dp    = (const float*)d_in[8];
    float* out = (float*)d_out;

    k_fused<<<NB, NT, 0, stream>>>(x, Delta, A_re, A_im, B_re, B_im,
                                   C_re, C_im, Dp, out);
}